// Round 2
// baseline (385.573 us; speedup 1.0000x reference)
//
#include <hip/hip_runtime.h>
#include <hip/hip_fp16.h>
#include <stdint.h>

#define OUT_F 4096
#define IN_F  4096
#define M_DIM 8192
#define K_DIM IN_F
#define N_DIM OUT_F
#define GROUPS (OUT_F * IN_F / 64)     // 262144
#define NTRIP  (GROUPS * 8)            // 2097152 triplets (3 bytes -> 8 weights)
#define NPARAM (GROUPS * 2)            // 524288 param scalars

typedef __attribute__((ext_vector_type(4))) float f32x4;
typedef __attribute__((ext_vector_type(8))) short bf16x8;
typedef __attribute__((ext_vector_type(8))) unsigned short u16x8;

static __device__ __forceinline__ unsigned short f32_to_bf16(float f) {
    unsigned int u = __builtin_bit_cast(unsigned int, f);
    u += 0x7fffu + ((u >> 16) & 1u);     // RNE
    return (unsigned short)(u >> 16);
}

// ---------------- params dtype detection (f16 vs f32 on device) ----------------
__global__ void flag_init(int* f) { f[0] = 0; }

// Reads the first NPARAM halfs (1 MB) — safe whether buffer is 1 MB (f16) or
// 2 MB (f32). True-f16 data: |lo|,|hi| <= ~0.1 by construction -> flag stays 0.
// f32 data read as halves: hi-halves of ~0.02 floats are 0x3Cxx (>=1.0) -> flag=1.
__global__ __launch_bounds__(256) void detect_f16(const __half* __restrict__ p,
                                                  int* __restrict__ flag) {
    int big = 0;
    for (int i = blockIdx.x * 256 + threadIdx.x; i < NPARAM; i += 256 * 256) {
        float v = __half2float(p[i]);
        if (!(fabsf(v) < 1.0f)) big = 1;   // catches >=1, inf, NaN
    }
    if (big) atomicOr(flag, 1);
}

// ---------------- dequant: 3-bit packed -> bf16 W[N][K] row-major ----------------
__global__ __launch_bounds__(256) void dequant3(const int* __restrict__ pk,
                                                const void* __restrict__ params,
                                                const int* __restrict__ flag,
                                                unsigned short* __restrict__ W) {
    int t = blockIdx.x * 256 + threadIdx.x;          // triplet id, exact grid
    int b0 = pk[3 * t + 0];
    int b1 = pk[3 * t + 1];
    int b2 = pk[3 * t + 2];
    int g = t >> 3;                                   // group id (8 triplets/group)
    float lo, hi;
    if (flag[0] == 0) {                               // params stored as f16
        const __half* p = (const __half*)params;
        lo = __half2float(p[2 * g + 0]);
        hi = __half2float(p[2 * g + 1]);
    } else {                                          // params stored as f32
        const float* p = (const float*)params;
        lo = p[2 * g + 0];
        hi = p[2 * g + 1];
    }
    float s = (hi - lo) * (1.0f / 7.0f);

    int q[8];
    q[0] = b0 & 7;
    q[1] = (b0 >> 3) & 7;
    q[2] = ((b0 >> 6) & 3) | ((b1 & 1) << 2);
    q[3] = (b1 >> 1) & 7;
    q[4] = (b1 >> 4) & 7;
    q[5] = ((b1 >> 7) & 1) | ((b2 & 3) << 1);
    q[6] = (b2 >> 2) & 7;
    q[7] = (b2 >> 5) & 7;

    u16x8 o;
#pragma unroll
    for (int j = 0; j < 8; j++) {
        float w = (float)q[j] * s + lo;
        o[j] = f32_to_bf16(w);
    }
    *(u16x8*)&W[8 * (size_t)t] = o;
}

// ---------------- x: f32 -> bf16 ----------------
__global__ __launch_bounds__(256) void cvt_x(const float* __restrict__ x,
                                             unsigned short* __restrict__ xb) {
    size_t t = (size_t)blockIdx.x * 256 + threadIdx.x;
    f32x4 a = *(const f32x4*)&x[8 * t];
    f32x4 b = *(const f32x4*)&x[8 * t + 4];
    u16x8 o;
#pragma unroll
    for (int j = 0; j < 4; j++) o[j] = f32_to_bf16(a[j]);
#pragma unroll
    for (int j = 0; j < 4; j++) o[4 + j] = f32_to_bf16(b[j]);
    *(u16x8*)&xb[8 * t] = o;
}

// ---------------- GEMM: C[M][N] = A[M][K] * B[N][K]^T + bias ----------------
#define BM 128
#define BN 128
#define BK 32

__global__ __launch_bounds__(256) void gemm_bt(const unsigned short* __restrict__ A,
                                               const unsigned short* __restrict__ B,
                                               const float* __restrict__ bias,
                                               float* __restrict__ C) {
    __shared__ unsigned short lsA[BM * BK];   // 8 KB, row-major [128][32]
    __shared__ unsigned short lsB[BN * BK];   // 8 KB

    const int nbn = N_DIM / BN;                       // 32
    const int nwg = (M_DIM / BM) * nbn;               // 2048 (nwg % 8 == 0)
    int bid = blockIdx.x;
    int cpx = nwg >> 3;
    int swz = (bid & 7) * cpx + (bid >> 3);           // bijective XCD swizzle
    int bm = swz / nbn, bn = swz % nbn;

    const int row0 = bm * BM, col0 = bn * BN;
    const int t = threadIdx.x;
    const int lane = t & 63;
    const int wid = t >> 6;
    const int wr = wid >> 1, wc = wid & 1;            // 2x2 waves of 64x64

    const unsigned short* Abase = A + (size_t)row0 * K_DIM;
    const unsigned short* Bbase = B + (size_t)col0 * K_DIM;

    const int r  = lane & 15;
    const int ko = (lane >> 4) << 3;                  // k-offset 0/8/16/24

    f32x4 acc[4][4] = {};

    for (int kt = 0; kt < K_DIM; kt += BK) {
        // ---- stage A,B tiles via global_load_lds (16B/lane, linear LDS) ----
#pragma unroll
        for (int p = 0; p < 2; p++) {
            int idx  = p * 256 + t;                   // 0..511, 16B chunks
            int arow = idx >> 2;
            int ac   = idx & 3;
            const unsigned short* ga = Abase + (size_t)arow * K_DIM + kt + ac * 8;
            const unsigned short* gb = Bbase + (size_t)arow * K_DIM + kt + ac * 8;
            unsigned short* la = &lsA[(size_t)(p * 256 + wid * 64) * 8];  // wave-uniform base
            unsigned short* lb = &lsB[(size_t)(p * 256 + wid * 64) * 8];
            __builtin_amdgcn_global_load_lds((const __attribute__((address_space(1))) unsigned int*)ga,
                                             (__attribute__((address_space(3))) unsigned int*)la,
                                             16, 0, 0);
            __builtin_amdgcn_global_load_lds((const __attribute__((address_space(1))) unsigned int*)gb,
                                             (__attribute__((address_space(3))) unsigned int*)lb,
                                             16, 0, 0);
        }
        __syncthreads();

        // ---- fragments: row-major [row][32], lane r + k-group ko ----
        bf16x8 af[4], bfr[4];
#pragma unroll
        for (int mi = 0; mi < 4; mi++)
            af[mi] = *(const bf16x8*)&lsA[(wr * 64 + mi * 16 + r) * BK + ko];
#pragma unroll
        for (int ni = 0; ni < 4; ni++)
            bfr[ni] = *(const bf16x8*)&lsB[(wc * 64 + ni * 16 + r) * BK + ko];

#pragma unroll
        for (int mi = 0; mi < 4; mi++)
#pragma unroll
            for (int ni = 0; ni < 4; ni++)
                acc[mi][ni] = __builtin_amdgcn_mfma_f32_16x16x32_bf16(af[mi], bfr[ni], acc[mi][ni], 0, 0, 0);

        __syncthreads();
    }

    // ---- epilogue: C/D layout col=lane&15, row=(lane>>4)*4+j; fuse bias ----
    const int crow = (lane >> 4) * 4;
    const int ccol = lane & 15;
#pragma unroll
    for (int mi = 0; mi < 4; mi++) {
#pragma unroll
        for (int ni = 0; ni < 4; ni++) {
            int col = col0 + wc * 64 + ni * 16 + ccol;
            float bv = bias[col];
#pragma unroll
            for (int j = 0; j < 4; j++) {
                int rw = row0 + wr * 64 + mi * 16 + crow + j;
                C[(size_t)rw * N_DIM + col] = acc[mi][ni][j] + bv;
            }
        }
    }
}

// ws too small -> encode ws_size into d_out[0] for diagnosis
__global__ void ws_guard(float* out, float v) { out[0] = v; }

extern "C" void kernel_launch(void* const* d_in, const int* in_sizes, int n_in,
                              void* d_out, int out_size, void* d_ws, size_t ws_size,
                              hipStream_t stream) {
    const float* x      = (const float*)d_in[0];
    const int*   pk     = (const int*)d_in[1];
    const void*  params = (const void*)d_in[2];
    const float* bias   = (const float*)d_in[3];
    float* out = (float*)d_out;

    const size_t needW = (size_t)OUT_F * IN_F * 2;        // 33.5 MB bf16 W
    const size_t needX = (size_t)M_DIM * IN_F * 2;        // 67 MB bf16 x
    const size_t needF = 256;                             // detection flag
    if (ws_size < needW + needX + needF) {
        ws_guard<<<1, 1, 0, stream>>>(out, 1.0e6f + (float)(ws_size >> 20));
        return;
    }
    unsigned short* W  = (unsigned short*)d_ws;
    unsigned short* Xb = (unsigned short*)((char*)d_ws + needW);
    int*            fl = (int*)((char*)d_ws + needW + needX);

    flag_init<<<1, 1, 0, stream>>>(fl);
    detect_f16<<<256, 256, 0, stream>>>((const __half*)params, fl);
    dequant3<<<NTRIP / 256, 256, 0, stream>>>(pk, params, fl, W);
    cvt_x<<<(int)(((size_t)M_DIM * IN_F / 8) / 256), 256, 0, stream>>>(x, Xb);
    gemm_bt<<<(M_DIM / BM) * (N_DIM / BN), 256, 0, stream>>>(Xb, W, bias, out);
}

// Round 3
// 294.048 us; speedup vs baseline: 1.3113x; 1.3113x over previous
//
#include <hip/hip_runtime.h>
#include <hip/hip_fp16.h>
#include <stdint.h>

#define OUT_F 4096
#define IN_F  4096
#define M_DIM 8192
#define K_DIM IN_F
#define N_DIM OUT_F
#define GROUPS (OUT_F * IN_F / 64)
#define NTRIP  (GROUPS * 8)
#define NPARAM (GROUPS * 2)
#define NKT    (K_DIM / 64)      // 64 K-tiles
#define NIT    (NKT / 2)         // 32 iterations

typedef __attribute__((ext_vector_type(4))) float f32x4;
typedef __attribute__((ext_vector_type(8))) short bf16x8;
typedef __attribute__((ext_vector_type(8))) unsigned short u16x8;

static __device__ __forceinline__ unsigned short f32_to_bf16(float f) {
    unsigned int u = __builtin_bit_cast(unsigned int, f);
    u += 0x7fffu + ((u >> 16) & 1u);
    return (unsigned short)(u >> 16);
}

// ---------------- params dtype detection (f16 vs f32 on device) ----------------
__global__ void flag_init(int* f) { f[0] = 0; }

__global__ __launch_bounds__(256) void detect_f16(const __half* __restrict__ p,
                                                  int* __restrict__ flag) {
    int big = 0;
    for (int i = blockIdx.x * 256 + threadIdx.x; i < NPARAM; i += 256 * 256) {
        float v = __half2float(p[i]);
        if (!(fabsf(v) < 1.0f)) big = 1;
    }
    if (big) atomicOr(flag, 1);
}

// ---------------- dequant: 3-bit packed -> bf16 W[N][K] row-major ----------------
__global__ __launch_bounds__(256) void dequant3(const int* __restrict__ pk,
                                                const void* __restrict__ params,
                                                const int* __restrict__ flag,
                                                unsigned short* __restrict__ W) {
    int t = blockIdx.x * 256 + threadIdx.x;
    int b0 = pk[3 * t + 0];
    int b1 = pk[3 * t + 1];
    int b2 = pk[3 * t + 2];
    int g = t >> 3;
    float lo, hi;
    if (flag[0] == 0) {
        const __half* p = (const __half*)params;
        lo = __half2float(p[2 * g + 0]);
        hi = __half2float(p[2 * g + 1]);
    } else {
        const float* p = (const float*)params;
        lo = p[2 * g + 0];
        hi = p[2 * g + 1];
    }
    float s = (hi - lo) * (1.0f / 7.0f);

    int q[8];
    q[0] = b0 & 7;
    q[1] = (b0 >> 3) & 7;
    q[2] = ((b0 >> 6) & 3) | ((b1 & 1) << 2);
    q[3] = (b1 >> 1) & 7;
    q[4] = (b1 >> 4) & 7;
    q[5] = ((b1 >> 7) & 1) | ((b2 & 3) << 1);
    q[6] = (b2 >> 2) & 7;
    q[7] = (b2 >> 5) & 7;

    u16x8 o;
#pragma unroll
    for (int j = 0; j < 8; j++) {
        float w = (float)q[j] * s + lo;
        o[j] = f32_to_bf16(w);
    }
    *(u16x8*)&W[8 * (size_t)t] = o;
}

// ---------------- x: f32 -> bf16 ----------------
__global__ __launch_bounds__(256) void cvt_x(const float* __restrict__ x,
                                             unsigned short* __restrict__ xb) {
    size_t t = (size_t)blockIdx.x * 256 + threadIdx.x;
    f32x4 a = *(const f32x4*)&x[8 * t];
    f32x4 b = *(const f32x4*)&x[8 * t + 4];
    u16x8 o;
#pragma unroll
    for (int j = 0; j < 4; j++) o[j] = f32_to_bf16(a[j]);
#pragma unroll
    for (int j = 0; j < 4; j++) o[4 + j] = f32_to_bf16(b[j]);
    *(u16x8*)&xb[8 * t] = o;
}

// ============ 256x256 8-phase GEMM: C[M][N] = A[M][K]*B[N][K]^T + bias ============
// 8 waves (2M x 4N), per-wave 128x64 out. LDS 128 KiB: [buf][op][256*64] bf16.
// T2 swizzle: phys_byte = logical_byte ^ ((row&7)<<4), staged via pre-swizzled
// global source (linear gload_lds dest), same XOR on ds_read.

#define LDSA(buf) ((char*)&sh[buf][0][0])
#define LDSB(buf) ((char*)&sh[buf][1][0])

#define READ_A(buf, miq) do { _Pragma("unroll") for (int m2_ = 0; m2_ < 4; ++m2_) { \
    const char* p_ = LDSA(buf) + arow_b + ((miq)*4 + m2_) * 2048; \
    af[m2_][0] = *(const bf16x8*)(p_ + cb0); \
    af[m2_][1] = *(const bf16x8*)(p_ + cb1); } } while (0)

#define READ_B(buf, niq) do { _Pragma("unroll") for (int n2_ = 0; n2_ < 2; ++n2_) { \
    const char* p_ = LDSB(buf) + brow_b + ((niq)*2 + n2_) * 2048; \
    bf[n2_][0] = *(const bf16x8*)(p_ + cb0); \
    bf[n2_][1] = *(const bf16x8*)(p_ + cb1); } } while (0)

#define MFMA_Q(miq, niq) do { __builtin_amdgcn_s_setprio(1); \
  _Pragma("unroll") for (int m2_ = 0; m2_ < 4; ++m2_) \
  _Pragma("unroll") for (int n2_ = 0; n2_ < 2; ++n2_) { \
    acc[(miq)*4+m2_][(niq)*2+n2_] = __builtin_amdgcn_mfma_f32_16x16x32_bf16(af[m2_][0], bf[n2_][0], acc[(miq)*4+m2_][(niq)*2+n2_], 0,0,0); \
    acc[(miq)*4+m2_][(niq)*2+n2_] = __builtin_amdgcn_mfma_f32_16x16x32_bf16(af[m2_][1], bf[n2_][1], acc[(miq)*4+m2_][(niq)*2+n2_], 0,0,0); } \
  __builtin_amdgcn_s_setprio(0); } while (0)

// stage one operand tile (4 gload_lds): halves h=0,1 x chunks p=0,1
#define STAGE_OP(buf, opi, kt, G) do { \
  _Pragma("unroll") for (int h_ = 0; h_ < 2; ++h_) \
  _Pragma("unroll") for (int p_ = 0; p_ < 2; ++p_) { \
    const unsigned short* g_ = (G) + (((size_t)(h_*128 + p_*64 + sg_row)) << 12) + (size_t)(kt)*64 + sg_col; \
    unsigned short* l_ = &sh[buf][opi][h_*8192 + p_*4096 + w*512]; \
    __builtin_amdgcn_global_load_lds((const __attribute__((address_space(1))) unsigned int*)g_, \
        (__attribute__((address_space(3))) unsigned int*)l_, 16, 0, 0); } } while (0)

#define BAR() do { __builtin_amdgcn_sched_barrier(0); __builtin_amdgcn_s_barrier(); \
                   __builtin_amdgcn_sched_barrier(0); } while (0)
#define VMW(n) asm volatile("s_waitcnt vmcnt(" #n ")" ::: "memory")

__global__ __launch_bounds__(512, 1) void gemm8(const unsigned short* __restrict__ A,
                                                const unsigned short* __restrict__ B,
                                                const float* __restrict__ bias,
                                                float* __restrict__ C) {
    __shared__ unsigned short sh[2][2][16384];   // 128 KiB

    // bijective XCD swizzle: nwg = 512, cpx = 64
    int bid = blockIdx.x;
    int swz = (bid & 7) * 64 + (bid >> 3);
    int bm = swz >> 4, bn = swz & 15;            // 32 x 16 tiles
    const int row0 = bm * 256, col0 = bn * 256;

    const int t = threadIdx.x;
    const int lane = t & 63;
    const int w = t >> 6;
    const int wm = w >> 2, wn = w & 3;           // 2 x 4 waves, each 128x64

    // staging addressing (pre-swizzled global source, linear LDS dest)
    const int l_hi = lane >> 3, l_lo = lane & 7;
    const int sg_row = w * 8 + l_hi;             // row within 64-row chunk
    const int sg_col = (l_lo ^ l_hi) * 8;        // swizzled col (elements)

    // fragment read addressing
    const int fr = lane & 15;
    const int kg = lane >> 4;
    const int swzb = (lane & 7) << 4;
    const int cb0 = (kg * 16) ^ swzb;            // ks=0 col byte (swizzled)
    const int cb1 = (64 + kg * 16) ^ swzb;       // ks=1
    const int arow_b = (wm * 128 + fr) * 128;    // A row base byte
    const int brow_b = (wn * 64 + fr) * 128;     // B row base byte

    const unsigned short* GA = A + (size_t)row0 * K_DIM;
    const unsigned short* GB = B + (size_t)col0 * K_DIM;

    f32x4 acc[8][4] = {};
    bf16x8 af[4][2], bf[2][2];

    // prologue: X(buf0) <- tile0 A,B ; Y(buf1) <- tile1 A   (12 loads)
    STAGE_OP(0, 0, 0, GA);
    STAGE_OP(0, 1, 0, GB);
    STAGE_OP(1, 0, 1, GA);
    VMW(4);                    // X complete; Y.A may remain in flight
    BAR();

    for (int it = 0; it < NIT; ++it) {
        const int ktx = 2 * it;
        const bool pf = (it + 1 < NIT);

        // ph1: X q(0,0); stage Y.B <- tile ktx+1
        READ_A(0, 0); READ_B(0, 0);
        STAGE_OP(1, 1, ktx + 1, GB);
        BAR(); MFMA_Q(0, 0); BAR();
        // ph2: X q(0,1)
        READ_B(0, 1);
        BAR(); MFMA_Q(0, 1); BAR();
        // ph3: X q(1,1)
        READ_A(0, 1);
        BAR(); MFMA_Q(1, 1); BAR();
        // ph4: X q(1,0); stage X.A <- tile ktx+2; counted vmcnt
        READ_B(0, 0);
        if (pf) { STAGE_OP(0, 0, ktx + 2, GA); VMW(4); }
        else    { VMW(0); }
        BAR(); MFMA_Q(1, 0); BAR();
        // ph5: Y q(0,0); stage X.B <- tile ktx+2
        READ_A(1, 0); READ_B(1, 0);
        if (pf) STAGE_OP(0, 1, ktx + 2, GB);
        BAR(); MFMA_Q(0, 0); BAR();
        // ph6: Y q(0,1)
        READ_B(1, 1);
        BAR(); MFMA_Q(0, 1); BAR();
        // ph7: Y q(1,1)
        READ_A(1, 1);
        BAR(); MFMA_Q(1, 1); BAR();
        // ph8: Y q(1,0); stage Y.A <- tile ktx+3; counted vmcnt
        READ_B(1, 0);
        if (pf) { STAGE_OP(1, 0, ktx + 3, GA); VMW(4); }
        else    { VMW(0); }
        BAR(); MFMA_Q(1, 0); BAR();
    }

    // epilogue: C/D layout col=lane&15, row=(lane>>4)*4+j; fuse bias
    const int crow = kg * 4;
    const int ccol = fr;
#pragma unroll
    for (int mi = 0; mi < 8; ++mi) {
#pragma unroll
        for (int ni = 0; ni < 4; ++ni) {
            int col = col0 + wn * 64 + ni * 16 + ccol;
            float bv = bias[col];
#pragma unroll
            for (int j = 0; j < 4; ++j) {
                int rw = row0 + wm * 128 + mi * 16 + crow + j;
                C[(size_t)rw * N_DIM + col] = acc[mi][ni][j] + bv;
            }
        }
    }
}

__global__ void ws_guard(float* out, float v) { out[0] = v; }

extern "C" void kernel_launch(void* const* d_in, const int* in_sizes, int n_in,
                              void* d_out, int out_size, void* d_ws, size_t ws_size,
                              hipStream_t stream) {
    const float* x      = (const float*)d_in[0];
    const int*   pk     = (const int*)d_in[1];
    const void*  params = (const void*)d_in[2];
    const float* bias   = (const float*)d_in[3];
    float* out = (float*)d_out;

    const size_t needW = (size_t)OUT_F * IN_F * 2;
    const size_t needX = (size_t)M_DIM * IN_F * 2;
    const size_t needF = 256;
    if (ws_size < needW + needX + needF) {
        ws_guard<<<1, 1, 0, stream>>>(out, 1.0e6f + (float)(ws_size >> 20));
        return;
    }
    unsigned short* W  = (unsigned short*)d_ws;
    unsigned short* Xb = (unsigned short*)((char*)d_ws + needW);
    int*            fl = (int*)((char*)d_ws + needW + needX);

    flag_init<<<1, 1, 0, stream>>>(fl);
    detect_f16<<<256, 256, 0, stream>>>((const __half*)params, fl);
    dequant3<<<NTRIP / 256, 256, 0, stream>>>(pk, params, fl, W);
    cvt_x<<<(int)(((size_t)M_DIM * IN_F / 8) / 256), 256, 0, stream>>>(x, Xb);
    gemm8<<<(M_DIM / 256) * (N_DIM / 256), 512, 0, stream>>>(Xb, W, bias, out);
}